// Round 8
// baseline (127.255 us; speedup 1.0000x reference)
//
#include <hip/hip_runtime.h>

// Problem constants (reference: B,T,D,O = 16,1024,1024,10; T==D required)
#define BB 16
#define TT 1024
#define DD 1024
#define OO 10
#define ROWS 64

// ---------------------------------------------------------------------------
// R21 (this): R20 (117.2us: 1024-thr/16-wave blocks, ROWS=64, grid 256=1/CU)
// with the operand path moved OFF the LDS pipe: W / u-slab read directly
// from global (L2-resident: W=40KB hot, u[b]=40KB) inside the FMA loop.
// Deletes per block: 40KB staging read+write, one barrier, ~800 of 880
// LDS-pipe ops per wave (ds_read_b128 broadcasts moved only 128B unique
// through a 1KB-capable crossbar). LDS keeps only part[]+zred combine.
// Mechanism evidence: pass1(HBM)==pass2(L3)==17.5us -> not data-path-bound;
// 8->16 waves gave only -6% -> not latency-bound; issue-slot model ~2.5us
// -> LDS pipe is the largest unprobed consumer, identical in every variant
// so far. Z summation order + all FMA orders unchanged -> bitwise absmax.
//
// If this washes (+-1us): plateau is vmem/issue-structural; declare floor =
// 82us unconditional fills + 2x17.5us passes (six structural variants all
// within 6%). If it regresses (operand latency): revert R20.
//
// REFUTED AS A CLASS: register-persistent X (R17/R18/R19: hipcc always
// targets max occupancy, spills persistent tiles; launch_bounds 2nd arg
// unreliable). Also refuted: grid.sync fusion (R8/R15: ~45us/sync),
// ws-avoidance (R15: 2x41us 256MiB poison fills UNCONDITIONAL = 82us harness
// floor), per-chunk LDS staging barriers (R6), per-block softmax fold (R9),
// non-temporal X loads (R11), depth-4 prefetch (R12), ROWS=32 split (R13),
// 16-lane/256B chunks + ROWS=16 (R14).
// ---------------------------------------------------------------------------
template <bool FIRST>
__global__ __launch_bounds__(1024) void gemm10_kernel(
    const float* __restrict__ X,     // (B,T,D) logits
    const float* __restrict__ Wop,   // FIRST: W (O,D); else u (B,O,T)
    const float* __restrict__ bias,  // FIRST only
    float* __restrict__ Y)           // FIRST: u (B,O,T); else out (B,O,T)
{
    __shared__ float part[4][ROWS][OO];   // 10 KB
    __shared__ float zred[OO];            // 40 B (pass2: softmax denom)

    const int b   = blockIdx.y;
    const int t0  = blockIdx.x * ROWS;
    const int tid = threadIdx.x;          // 0..1023

    const int wv16 = tid >> 6;       // wave 0..15
    const int w    = wv16 & 3;       // d quarter
    const int rq   = wv16 >> 2;      // row quarter (0..3)
    const int lane = tid & 63;
    const int l    = lane & 7;       // d-slice within row (8 lanes x 16B)
    const int g    = lane >> 3;      // row group 0..7
    const int dofs = w * 256 + l * 4;
    const int rb   = rq * 16;

    // operand base (global): W for pass1, u[b] slab for pass2
    const float* op = Wop + (FIRST ? 0 : (size_t)b * OO * TT);

    if (!FIRST) {
        // Z[b,o] = sum_t u[b,o,t], read directly from global (L2/L3-hot;
        // summation order identical to the previous LDS-slab version).
        // Wave wv16 = o (0..9). zred visibility at the epilogue is covered
        // by the pre-epilogue __syncthreads.
        if (wv16 < OO) {
            float s = 0.f;
#pragma unroll
            for (int q = 0; q < 4; ++q) {
                const float4 v =
                    *(const float4*)(op + (size_t)wv16 * TT + (lane * 4 + q) * 4);
                s += v.x + v.y + v.z + v.w;
            }
#pragma unroll
            for (int off = 32; off > 0; off >>= 1)
                s += __shfl_down(s, off, 64);
            if (lane == 0) zred[wv16] = s;
        }
    }

    // Thread's rows: t0 + rb + g + 8j, j = 0..1.
    const float* xp[2];
#pragma unroll
    for (int j = 0; j < 2; ++j)
        xp[j] = X + ((size_t)b * TT + t0 + rb + g + 8 * j) * DD + dofs;
    const float* opl = op + dofs;    // per-thread operand slice base

    float acc[2][OO];
#pragma unroll
    for (int j = 0; j < 2; ++j)
#pragma unroll
        for (int o = 0; o < OO; ++o) acc[j][o] = 0.f;

    // 2-deep prefetch of the logits slices
    float4 x0[2], x1[2];
#pragma unroll
    for (int j = 0; j < 2; ++j) {
        x0[j] = *(const float4*)(xp[j]);
        x1[j] = *(const float4*)(xp[j] + 32);
    }

#pragma unroll 1
    for (int it = 0; it < 8; it += 2) {
        float4 c0[2];
#pragma unroll
        for (int j = 0; j < 2; ++j) c0[j] = x0[j];
        if (it < 6) {
#pragma unroll
            for (int j = 0; j < 2; ++j)
                x0[j] = *(const float4*)(xp[j] + (it + 2) * 32);
        }
        {
            const float* wp = opl + it * 32;
#pragma unroll
            for (int o = 0; o < OO; ++o) {
                const float4 wv = *(const float4*)(wp + o * DD);
#pragma unroll
                for (int j = 0; j < 2; ++j)
                    acc[j][o] += c0[j].x * wv.x + c0[j].y * wv.y +
                                 c0[j].z * wv.z + c0[j].w * wv.w;
            }
        }
#pragma unroll
        for (int j = 0; j < 2; ++j) c0[j] = x1[j];
        if (it < 5) {
#pragma unroll
            for (int j = 0; j < 2; ++j)
                x1[j] = *(const float4*)(xp[j] + (it + 3) * 32);
        }
        {
            const float* wp = opl + (it + 1) * 32;
#pragma unroll
            for (int o = 0; o < OO; ++o) {
                const float4 wv = *(const float4*)(wp + o * DD);
#pragma unroll
                for (int j = 0; j < 2; ++j)
                    acc[j][o] += c0[j].x * wv.x + c0[j].y * wv.y +
                                 c0[j].z * wv.z + c0[j].w * wv.w;
            }
        }
    }

    // 3-level reduction within each 8-lane group, then cross-wave via LDS.
#pragma unroll
    for (int j = 0; j < 2; ++j) {
#pragma unroll
        for (int o = 0; o < OO; ++o) {
            float v = acc[j][o];
            v += __shfl_down(v, 4, 8);
            v += __shfl_down(v, 2, 8);
            v += __shfl_down(v, 1, 8);
            if (l == 0) part[w][rb + j * 8 + g][o] = v;
        }
    }
    __syncthreads();

    // 64 rows x 10 o = 640 outputs; threads 0..639
    if (tid < ROWS * OO) {
        const int row = tid / OO;
        const int o   = tid % OO;
        float v = part[0][row][o] + part[1][row][o] +
                  part[2][row][o] + part[3][row][o];
        if (FIRST) {
            // u = exp((dot + bias)/O); |arg| < ~0.5 -> max-free exp is safe
            Y[((size_t)b * OO + o) * TT + (t0 + row)] =
                __expf((v + bias[o]) * (1.0f / OO));
        } else {
            Y[((size_t)b * OO + o) * TT + (t0 + row)] = v / zred[o];
        }
    }
}

extern "C" void kernel_launch(void* const* d_in, const int* in_sizes, int n_in,
                              void* d_out, int out_size, void* d_ws, size_t ws_size,
                              hipStream_t stream)
{
    const float* logits = (const float*)d_in[0];
    // d_in[1] = decision — unused by the forward math
    const float* W    = (const float*)d_in[2];
    const float* bias = (const float*)d_in[3];
    float* out = (float*)d_out;
    float* u   = (float*)d_ws;      // B*O*T floats = 655 KB

    dim3 grid(TT / ROWS, BB);       // (16, 16) = 256 blocks = 1/CU
    // K1: u = exp((X.W^T + b)/O)   (kernel boundary = fence)
    gemm10_kernel<true><<<grid, 1024, 0, stream>>>(logits, W, bias, u);
    // K3: Z from global u; out = (X.u) / Z
    gemm10_kernel<false><<<grid, 1024, 0, stream>>>(logits, u, nullptr, out);
}

// Round 9
// 116.041 us; speedup vs baseline: 1.0966x; 1.0966x over previous
//
#include <hip/hip_runtime.h>

// Problem constants (reference: B,T,D,O = 16,1024,1024,10; T==D required)
#define BB 16
#define TT 1024
#define DD 1024
#define OO 10
#define ROWS 64

// ---------------------------------------------------------------------------
// R22 (this): R20 (proven 117.2us: two kernels, 1024-thr/16-wave blocks,
// ROWS=64, grid 256=1/CU, LDS operand staging) + ONE change: coalesced
// epilogue stores. Old mapping o=tid%10,row=tid/10 -> consecutive lanes
// write t-neighbors at 4KB-strided o -> each wave store scatters to ~26
// transactions + L2 partial-line merges (640 scattered 4B singles/block/
// pass). New mapping o=tid>>6,row=tid&63 -> each wave writes contiguous
// 256B runs (and kills the div/mod). Store pipe is the last unprobed pipe.
//
// R21 refuted: global-L2 operand reads cost +5us/pass vs LDS staging ->
// LDS broadcast transport is optimal here; reverted.
//
// REFUTED AS A CLASS: register-persistent X (R17/R18/R19: hipcc targets max
// occupancy and spills persistent tiles; launch_bounds 2nd arg unreliable).
// Also refuted: grid.sync fusion (R8/R15: ~45us/sync), ws-avoidance (R15:
// 2x41us 256MiB poison fills UNCONDITIONAL = 82us harness floor), per-chunk
// staging barriers (R6), per-block softmax fold (R9), non-temporal X loads
// (R11), depth-4 prefetch (R12), ROWS=32 split (R13), 16-lane/256B chunks
// (R14), global operand reads (R21).
//
// If this washes: all pipes probed; 82us fills + 2x17.5us passes is the
// floor for this access shape -> declare roofline.
// ---------------------------------------------------------------------------
template <bool FIRST>
__global__ __launch_bounds__(1024) void gemm10_kernel(
    const float* __restrict__ X,     // (B,T,D) logits
    const float* __restrict__ Wt,    // FIRST: W (O,D); else u (B,O,T)
    const float* __restrict__ bias,  // FIRST only
    float* __restrict__ Y)           // FIRST: u (B,O,T); else out (B,O,T)
{
    __shared__ float4 sW4[OO * 256];      // 40 KB operand ([o][t4])
    __shared__ float  part[4][ROWS][OO];  // 10 KB
    __shared__ float  zred[OO];           // 40 B (pass2: softmax denom)

    const int b   = blockIdx.y;
    const int t0  = blockIdx.x * ROWS;
    const int tid = threadIdx.x;          // 0..1023

    // ---- stage operand -> LDS (2560 float4, contiguous, coalesced) ----
    {
        const float4* src = (const float4*)(Wt + (FIRST ? 0 : (size_t)b * OO * TT));
        for (int idx = tid; idx < OO * 256; idx += 1024)
            sW4[idx] = src[idx];
    }
    __syncthreads();

    const int wv16 = tid >> 6;       // wave 0..15
    const int w    = wv16 & 3;       // d quarter
    const int rq   = wv16 >> 2;      // row quarter (0..3) -> rows rq*16..+15
    const int lane = tid & 63;
    const int l    = lane & 7;       // d-slice within row (8 lanes x 16B)
    const int g    = lane >> 3;      // row group 0..7
    const int dofs = w * 256 + l * 4;
    const int rb   = rq * 16;

    if (!FIRST) {
        // Z[b,o] = sum_t u from the staged slab. Wave wv16 = o (0..9).
        // zred visibility at the epilogue is covered by the pre-epilogue
        // __syncthreads.
        if (wv16 < OO) {
            float s = 0.f;
#pragma unroll
            for (int q = 0; q < 4; ++q) {
                const float4 v = sW4[wv16 * 256 + lane * 4 + q];
                s += v.x + v.y + v.z + v.w;
            }
#pragma unroll
            for (int off = 32; off > 0; off >>= 1)
                s += __shfl_down(s, off, 64);
            if (lane == 0) zred[wv16] = s;
        }
    }

    // Thread's rows: t0 + rb + g + 8j, j = 0..1 (covers this quarter's 16).
    const float* xp[2];
#pragma unroll
    for (int j = 0; j < 2; ++j)
        xp[j] = X + ((size_t)b * TT + t0 + rb + g + 8 * j) * DD + dofs;
    const float* sWl = (const float*)sW4 + dofs;

    float acc[2][OO];
#pragma unroll
    for (int j = 0; j < 2; ++j)
#pragma unroll
        for (int o = 0; o < OO; ++o) acc[j][o] = 0.f;

    // 2-deep prefetch of the logits slices
    float4 x0[2], x1[2];
#pragma unroll
    for (int j = 0; j < 2; ++j) {
        x0[j] = *(const float4*)(xp[j]);
        x1[j] = *(const float4*)(xp[j] + 32);
    }

#pragma unroll 1
    for (int it = 0; it < 8; it += 2) {
        float4 c0[2];
#pragma unroll
        for (int j = 0; j < 2; ++j) c0[j] = x0[j];
        if (it < 6) {
#pragma unroll
            for (int j = 0; j < 2; ++j)
                x0[j] = *(const float4*)(xp[j] + (it + 2) * 32);
        }
        {
            const float* wp = sWl + it * 32;
#pragma unroll
            for (int o = 0; o < OO; ++o) {
                const float4 wv = *(const float4*)(wp + o * DD);
#pragma unroll
                for (int j = 0; j < 2; ++j)
                    acc[j][o] += c0[j].x * wv.x + c0[j].y * wv.y +
                                 c0[j].z * wv.z + c0[j].w * wv.w;
            }
        }
#pragma unroll
        for (int j = 0; j < 2; ++j) c0[j] = x1[j];
        if (it < 5) {
#pragma unroll
            for (int j = 0; j < 2; ++j)
                x1[j] = *(const float4*)(xp[j] + (it + 3) * 32);
        }
        {
            const float* wp = sWl + (it + 1) * 32;
#pragma unroll
            for (int o = 0; o < OO; ++o) {
                const float4 wv = *(const float4*)(wp + o * DD);
#pragma unroll
                for (int j = 0; j < 2; ++j)
                    acc[j][o] += c0[j].x * wv.x + c0[j].y * wv.y +
                                 c0[j].z * wv.z + c0[j].w * wv.w;
            }
        }
    }

    // 3-level reduction within each 8-lane group, then cross-wave via LDS.
#pragma unroll
    for (int j = 0; j < 2; ++j) {
#pragma unroll
        for (int o = 0; o < OO; ++o) {
            float v = acc[j][o];
            v += __shfl_down(v, 4, 8);
            v += __shfl_down(v, 2, 8);
            v += __shfl_down(v, 1, 8);
            if (l == 0) part[w][rb + j * 8 + g][o] = v;
        }
    }
    __syncthreads();

    // 640 outputs; COALESCED mapping: o = tid>>6 (0..9), row = tid&63 ->
    // each wave writes one o's 64 consecutive t (256B run). Threads 0..639.
    if (tid < ROWS * OO) {
        const int o   = tid >> 6;
        const int row = tid & 63;
        float v = part[0][row][o] + part[1][row][o] +
                  part[2][row][o] + part[3][row][o];
        if (FIRST) {
            // u = exp((dot + bias)/O); |arg| < ~0.5 -> max-free exp is safe
            Y[((size_t)b * OO + o) * TT + (t0 + row)] =
                __expf((v + bias[o]) * (1.0f / OO));
        } else {
            Y[((size_t)b * OO + o) * TT + (t0 + row)] = v / zred[o];
        }
    }
}

extern "C" void kernel_launch(void* const* d_in, const int* in_sizes, int n_in,
                              void* d_out, int out_size, void* d_ws, size_t ws_size,
                              hipStream_t stream)
{
    const float* logits = (const float*)d_in[0];
    // d_in[1] = decision — unused by the forward math
    const float* W    = (const float*)d_in[2];
    const float* bias = (const float*)d_in[3];
    float* out = (float*)d_out;
    float* u   = (float*)d_ws;      // B*O*T floats = 655 KB

    dim3 grid(TT / ROWS, BB);       // (16, 16) = 256 blocks = 1/CU
    // K1: u = exp((X.W^T + b)/O)   (kernel boundary = fence)
    gemm10_kernel<true><<<grid, 1024, 0, stream>>>(logits, W, bias, u);
    // K3: Z computed in-block from the staged slab; out = (X.u) / Z
    gemm10_kernel<false><<<grid, 1024, 0, stream>>>(logits, u, nullptr, out);
}